// Round 2
// baseline (1261.370 us; speedup 1.0000x reference)
//
#include <hip/hip_runtime.h>
#include <cstddef>

// TransitionDown: B=16 clouds, P=4096 pts, S=1024 fps samples, K=16 knn,
// IN_F=256, OUT_F=512.
// Pipeline:
//   L1 fused: blocks[0,8)    FPS, TWO clouds per block (waves 0-3 cloud A,
//                            waves 4-7 cloud B): the two serial argmax chains
//                            interleave on the SIMDs and share one barrier,
//                            amortizing the fixed per-step latency.
//             blocks[8,1032) MLP GEMM fp32 -> h bf16 (hidden under FPS)
//             blocks[1032,2056) xx[i]=||f_i||^2 + fp16 hi/lo split of feat
//   L2: BN partial sums over h   L3: BN finalize -> scale/shift
//   L4: KNN via fp16-split MFMA (S = QhXh + QhXl + QlXh), per-segment top-16
//       (stages precomputed XH/XL: half the bytes, no cvt in the hot loop)
//   L5: exact 4-way merge of segment partials -> NN
//   L6: gather + BN + ReLU + max over K (4 queries/block, cloud-grouped)

#define TD_B   16
#define TD_P   4096
#define TD_S   1024
#define TD_K   16
#define TD_INF 256
#define TD_OUTF 512

typedef __attribute__((ext_vector_type(8))) _Float16 half8;
typedef __attribute__((ext_vector_type(4))) _Float16 half4;
typedef __attribute__((ext_vector_type(4))) float    f32x4;
typedef __attribute__((ext_vector_type(2))) float    v2f;

__device__ __forceinline__ unsigned short f2bf(float x) {
    unsigned u = __float_as_uint(x);
    unsigned r = (u + 0x7fffu + ((u >> 16) & 1u)) >> 16;   // RNE
    return (unsigned short)r;
}

struct FpsSm {
    float4 p4[2][TD_P];            // 128 KB: (x,y,z,-) per point, per cloud
    int    sel[2][TD_S];           // 8 KB
    unsigned long long kw[2][2][4];  // [parity][cloud][wave-in-cloud]
};
struct GemmSm {
    float As[16 * 260];   // [k][m]
    float Bs[16 * 128];   // [k][n]
};
union SmU {
    FpsSm f; GemmSm g;
    char pad_[139500];    // 1 block/CU everywhere; FPS keeps a private CU
};

// One level of a wave64 max-reduce on a positive-double key via paired 32-bit
// DPP + v_max_f64 (keys are finite positive doubles: hi=fp32 bits of min_d,
// lo=~idx, so fmax == bitwise u64 max). Result valid in lane 63 after
// shr 1,2,4,8 + bcast15 + bcast31.
#define TD_DPPSTEPD(kd_, ctl, bc)                                                       \
    {                                                                                   \
        long long ki_ = __double_as_longlong(kd_);                                      \
        unsigned yh_ = (unsigned)__builtin_amdgcn_update_dpp(                           \
            0, (int)((unsigned long long)ki_ >> 32), (ctl), 0xf, 0xf, (bc));            \
        unsigned yl_ = (unsigned)__builtin_amdgcn_update_dpp(                           \
            0, (int)(unsigned)(unsigned long long)ki_, (ctl), 0xf, 0xf, (bc));          \
        kd_ = fmax(kd_, __hiloint2double((int)yh_, (int)yl_));                          \
    }

__global__ __launch_bounds__(512)
void td_fused(const float* __restrict__ feat, const float* __restrict__ pos,
              const float* __restrict__ W, const float* __restrict__ bias,
              unsigned short* __restrict__ H, float* __restrict__ XX,
              int* __restrict__ FPSI, float* __restrict__ outP,
              float* __restrict__ outB,
              _Float16* __restrict__ XH, _Float16* __restrict__ XL) {
    __shared__ SmU sm;
    const int bx = blockIdx.x;
    const int t  = threadIdx.x;

    if (bx < 8) {
        // ---------------- FPS: two clouds per block ---------------------------
        // g = cloud slot (waves 0-3 -> A, 4-7 -> B), tc = thread-in-cloud.
        // Each thread owns 16 pts as 8 packed v2f lanes (contract off =>
        // np-bitwise sub,sq,sq,sq,add,add,min per element). key = double
        // (hi=fp32 bits of min_d, lo=~p): fmax => largest d, tie -> lowest p.
        // The A-chain's DPP/LDS stalls hide under the B-wave's issue on the
        // same SIMD; one barrier retires one step of BOTH clouds.
        __builtin_amdgcn_s_setprio(2);
        const int g    = t >> 8;          // cloud slot 0/1
        const int tc   = t & 255;         // thread within cloud group
        const int wc   = (t >> 6) & 3;    // wave within cloud group
        const int lane = t & 63;
        const int b    = bx * 2 + g;      // global cloud id
        v2f px[8], py[8], pz[8], md[8];
        int ni0[8], ni1[8];
        float lx, ly, lz;
#pragma unroll
        for (int j = 0; j < 8; ++j) {
            int p0 = j * 512 + tc, p1 = p0 + 256;
            const float* q0 = pos + (size_t)(b * TD_P + p0) * 3;
            const float* q1 = pos + (size_t)(b * TD_P + p1) * 3;
            float x0 = q0[0], y0 = q0[1], z0 = q0[2];
            float x1 = q1[0], y1 = q1[1], z1 = q1[2];
            px[j] = (v2f){x0, x1}; py[j] = (v2f){y0, y1}; pz[j] = (v2f){z0, z1};
            sm.f.p4[g][p0] = make_float4(x0, y0, z0, 0.0f);
            sm.f.p4[g][p1] = make_float4(x1, y1, z1, 0.0f);
            md[j] = (v2f){__builtin_inff(), __builtin_inff()};
            ni0[j] = ~p0; ni1[j] = ~p1;
        }
        if (tc == 0) sm.f.sel[g][0] = 0;
        __syncthreads();
        { float4 wp = sm.f.p4[g][0]; lx = wp.x; ly = wp.y; lz = wp.z; }
        for (int s = 0; s < TD_S - 1; ++s) {
            const int par = s & 1;
            double k[16];
            {
#pragma clang fp contract(off)
                v2f l2x = (v2f){lx, lx}, l2y = (v2f){ly, ly}, l2z = (v2f){lz, lz};
#pragma unroll
                for (int j = 0; j < 8; ++j) {
                    v2f dx = px[j] - l2x;
                    v2f dy = py[j] - l2y;
                    v2f dz = pz[j] - l2z;
                    v2f sx = dx * dx;
                    v2f sy = dy * dy;
                    v2f sz = dz * dz;
                    v2f dd = (sx + sy) + sz;
                    md[j] = __builtin_elementwise_min(md[j], dd);
                    k[2 * j]     = __hiloint2double(__float_as_int(md[j].x), ni0[j]);
                    k[2 * j + 1] = __hiloint2double(__float_as_int(md[j].y), ni1[j]);
                }
            }
            // in-thread tree (15 v_max_f64)
#pragma unroll
            for (int st = 8; st > 0; st >>= 1)
#pragma unroll
                for (int i = 0; i < st; ++i) k[i] = fmax(k[i], k[i + st]);
            double tk = k[0];
            TD_DPPSTEPD(tk, 0x111, true)    // row_shr:1
            TD_DPPSTEPD(tk, 0x112, true)    // row_shr:2
            TD_DPPSTEPD(tk, 0x114, true)    // row_shr:4
            TD_DPPSTEPD(tk, 0x118, true)    // row_shr:8
            TD_DPPSTEPD(tk, 0x142, false)   // row_bcast:15
            TD_DPPSTEPD(tk, 0x143, false)   // row_bcast:31
            if (lane == 63) sm.f.kw[par][g][wc] = (unsigned long long)__double_as_longlong(tk);
            __syncthreads();
            {
                // 4 wave keys of MY cloud as 2x double2 (b128), 3-deep fmax.
                const double2* kd = (const double2*)sm.f.kw[par][g];
                double2 va = kd[0], vb = kd[1];
                double gk = fmax(fmax(va.x, va.y), fmax(vb.x, vb.y));
                unsigned idx = ~(unsigned)__double2loint(gk);
                if (tc == 0) sm.f.sel[g][s + 1] = (int)idx;
                float4 wp = sm.f.p4[g][idx];
                lx = wp.x; ly = wp.y; lz = wp.z;
            }
        }
        __syncthreads();
        for (int s = tc; s < TD_S; s += 256) {
            int li = sm.f.sel[g][s];
            int og = b * TD_S + s;
            float4 wp = sm.f.p4[g][li];
            outP[og * 3 + 0] = wp.x;
            outP[og * 3 + 1] = wp.y;
            outP[og * 3 + 2] = wp.z;
            outB[og] = (float)b;
            FPSI[og] = b * TD_P + li;   // global row index
        }
    } else if (bx < 8 + 1024) {
        // ---------------- MLP GEMM: 256x128 tile, 512 thr, 8x8 micro ---------
        const int gb = bx - 8;
        const int mb = gb >> 2, nb = gb & 3;
        const int tm = t >> 4, tn = t & 15;
        float acc[8][8];
#pragma unroll
        for (int i = 0; i < 8; ++i)
#pragma unroll
            for (int j = 0; j < 8; ++j) acc[i][j] = 0.0f;
        float* As = sm.g.As;
        float* Bs = sm.g.Bs;
        for (int kc = 0; kc < 16; ++kc) {
#pragma unroll
            for (int p2 = 0; p2 < 2; ++p2) {
                int f4 = t + 512 * p2;
                int r = f4 >> 2, c4 = f4 & 3;
                float4 v = *(const float4*)&feat[(size_t)(mb * 256 + r) * 256 + kc * 16 + c4 * 4];
                As[(c4 * 4 + 0) * 260 + r] = v.x;
                As[(c4 * 4 + 1) * 260 + r] = v.y;
                As[(c4 * 4 + 2) * 260 + r] = v.z;
                As[(c4 * 4 + 3) * 260 + r] = v.w;
            }
            {
                int kk = t >> 5, n4 = t & 31;
                float4 v = *(const float4*)&W[(size_t)(kc * 16 + kk) * 512 + nb * 128 + n4 * 4];
                *(float4*)&Bs[kk * 128 + n4 * 4] = v;
            }
            __syncthreads();
#pragma unroll
            for (int kk = 0; kk < 16; ++kk) {
                float4 a0 = *(float4*)&As[kk * 260 + tm * 8];
                float4 a1 = *(float4*)&As[kk * 260 + tm * 8 + 4];
                float4 b0 = *(float4*)&Bs[kk * 128 + tn * 8];
                float4 b1 = *(float4*)&Bs[kk * 128 + tn * 8 + 4];
                float av[8] = {a0.x, a0.y, a0.z, a0.w, a1.x, a1.y, a1.z, a1.w};
                float bv2[8] = {b0.x, b0.y, b0.z, b0.w, b1.x, b1.y, b1.z, b1.w};
#pragma unroll
                for (int i = 0; i < 8; ++i)
#pragma unroll
                    for (int j = 0; j < 8; ++j)
                        acc[i][j] = fmaf(av[i], bv2[j], acc[i][j]);
            }
            __syncthreads();
        }
        float4 bb0 = *(const float4*)&bias[nb * 128 + tn * 8];
        float4 bb1 = *(const float4*)&bias[nb * 128 + tn * 8 + 4];
        float bsv[8] = {bb0.x, bb0.y, bb0.z, bb0.w, bb1.x, bb1.y, bb1.z, bb1.w};
#pragma unroll
        for (int i = 0; i < 8; ++i) {
            int row = mb * 256 + tm * 8 + i;
            uint4 pk;
            pk.x = (unsigned)f2bf(acc[i][0] + bsv[0]) | ((unsigned)f2bf(acc[i][1] + bsv[1]) << 16);
            pk.y = (unsigned)f2bf(acc[i][2] + bsv[2]) | ((unsigned)f2bf(acc[i][3] + bsv[3]) << 16);
            pk.z = (unsigned)f2bf(acc[i][4] + bsv[4]) | ((unsigned)f2bf(acc[i][5] + bsv[5]) << 16);
            pk.w = (unsigned)f2bf(acc[i][6] + bsv[6]) | ((unsigned)f2bf(acc[i][7] + bsv[7]) << 16);
            *(uint4*)&H[(size_t)row * 512 + nb * 128 + tn * 8] = pk;
        }
    } else {
        // -------- xx[i] = ||f_i||^2  +  fp16 hi/lo split of features ---------
        const int xb = bx - 1032;
        const int w = t >> 6, lane = t & 63;
#pragma unroll
        for (int it = 0; it < 8; ++it) {
            int r = xb * 64 + w * 8 + it;
            float4 v = *(const float4*)&feat[(size_t)r * 256 + lane * 4];
            float s = v.x * v.x + v.y * v.y + v.z * v.z + v.w * v.w;
#pragma unroll
            for (int off = 32; off > 0; off >>= 1) s += __shfl_down(s, off, 64);
            if (lane == 0) XX[r] = s;
            if (XH != nullptr) {
                half4 hh, hl;
                _Float16 h0 = (_Float16)v.x; hh[0] = h0; hl[0] = (_Float16)(v.x - (float)h0);
                _Float16 h1 = (_Float16)v.y; hh[1] = h1; hl[1] = (_Float16)(v.y - (float)h1);
                _Float16 h2 = (_Float16)v.z; hh[2] = h2; hl[2] = (_Float16)(v.z - (float)h2);
                _Float16 h3 = (_Float16)v.w; hh[3] = h3; hl[3] = (_Float16)(v.w - (float)h3);
                *(half4*)&XH[(size_t)r * 256 + lane * 4] = hh;
                *(half4*)&XL[(size_t)r * 256 + lane * 4] = hl;
            }
        }
    }
}

__global__ __launch_bounds__(256)
void td_stats(const unsigned short* __restrict__ H, float* __restrict__ P1,
              float* __restrict__ P2) {
    const int rb = blockIdx.x, t = threadIdx.x;   // 256 blocks x 256 rows
    float s1a = 0, s2a = 0, s1b = 0, s2b = 0;
    for (int r = 0; r < 256; ++r) {
        const unsigned* hp = (const unsigned*)(H + (size_t)(rb * 256 + r) * 512);
        unsigned u = hp[t];
        float lo = __uint_as_float(u << 16);
        float hi = __uint_as_float(u & 0xffff0000u);
        s1a += lo; s2a = fmaf(lo, lo, s2a);
        s1b += hi; s2b = fmaf(hi, hi, s2b);
    }
    P1[rb * 512 + 2 * t] = s1a; P1[rb * 512 + 2 * t + 1] = s1b;
    P2[rb * 512 + 2 * t] = s2a; P2[rb * 512 + 2 * t + 1] = s2b;
}

__global__ __launch_bounds__(512)
void td_bnfin(const float* __restrict__ P1, const float* __restrict__ P2,
              const float* __restrict__ gamma, const float* __restrict__ beta,
              float* __restrict__ SS) {
    const int ch = threadIdx.x;
    float s1 = 0, s2 = 0;
    for (int rb = 0; rb < 256; ++rb) { s1 += P1[rb * 512 + ch]; s2 += P2[rb * 512 + ch]; }
    const float invN = 1.0f / 65536.0f;
    float mu  = s1 * invN;
    float var = s2 * invN - mu * mu;
    float sc  = gamma[ch] * (1.0f / sqrtf(var + 1e-5f));
    float sh  = beta[ch] - mu * sc;
    SS[ch] = sc; SS[512 + ch] = sh;
}

// ---------------------------------------------------------------------------
// KNN via MFMA, fp16 split (hi/lo), 3-pass: S = QhXh + QhXl + QlXh.
// Grid 512 = 16 clouds x 8 q-groups(128q) x 4 candidate segments(1024c).
// Primary version stages precomputed XH/XL (pure fp16 copy, no cvt).
// ---------------------------------------------------------------------------
__global__ __launch_bounds__(256, 2)
void td_knn2h(const _Float16* __restrict__ XH, const _Float16* __restrict__ XL,
              const float* __restrict__ XX, const int* __restrict__ FPSI,
              float* __restrict__ PD, int* __restrict__ PI) {
    __shared__ union {
        _Float16 x[2][32][264];   // [hi/lo][c][k], row pad 8 halfs
        float    dt[128][33];     // aliased after MFMA: d values [q_local][c_local]
    } sm;
    __shared__ float QQs[128];
    __shared__ int   QR[128];

    const int bx = blockIdx.x, t = threadIdx.x;
    const int b = bx & 15, r2 = bx >> 4;          // r2 in [0,32)
    const int qq8 = r2 >> 2, seg = r2 & 3;
    const int cb = b * TD_P;
    const int segbase = cb + seg * 1024;

    if (t < 128) {   // query rows + norms
        int gr = FPSI[b * TD_S + qq8 * 128 + t];
        QR[t] = gr; QQs[t] = XX[gr];
    }
    __syncthreads();

    const int w = t >> 6, lane = t & 63;
    const int m = lane & 15, quad = lane >> 4;

    // ---- Q fragments into registers (A-op: lane holds Q[m][quad*8+j]) ------
    half8 qh[2][8], ql[2][8];
#pragma unroll
    for (int qs = 0; qs < 2; ++qs) {
        const size_t qr = (size_t)QR[w * 32 + qs * 16 + m] * 256;
        const _Float16* qph = XH + qr;
        const _Float16* qpl = XL + qr;
#pragma unroll
        for (int ks = 0; ks < 8; ++ks) {
            qh[qs][ks] = *(const half8*)(qph + ks * 32 + quad * 8);
            ql[qs][ks] = *(const half8*)(qpl + ks * 32 + quad * 8);
        }
    }

    float sd[16]; int si[16];
#pragma unroll
    for (int r = 0; r < 16; ++r) { sd[r] = __builtin_inff(); si[r] = 0x7fffffff; }

    const int xrow = t >> 3, part = t & 7;   // staging mapping

    for (int ct = 0; ct < 32; ++ct) {
        __syncthreads();   // prev selection done reading dt (aliases x)
        // ---- stage 32 candidates x 256 k (fp16 copy) -----------------------
        {
            const size_t ro = (size_t)(segbase + ct * 32 + xrow) * 256 + part * 32;
            const _Float16* xh = XH + ro;
            const _Float16* xl = XL + ro;
#pragma unroll
            for (int s2 = 0; s2 < 4; ++s2) {
                *(half8*)&sm.x[0][xrow][part * 32 + s2 * 8] = *(const half8*)(xh + s2 * 8);
                *(half8*)&sm.x[1][xrow][part * 32 + s2 * 8] = *(const half8*)(xl + s2 * 8);
            }
        }
        __syncthreads();
        // ---- MFMA: pass-major, 4 independent acc chains --------------------
        f32x4 acc[2][2];
        acc[0][0] = (f32x4)0.0f; acc[0][1] = (f32x4)0.0f;
        acc[1][0] = (f32x4)0.0f; acc[1][1] = (f32x4)0.0f;
#pragma unroll
        for (int ks = 0; ks < 8; ++ks) {
            half8 xh0 = *(half8*)&sm.x[0][m][ks * 32 + quad * 8];
            half8 xl0 = *(half8*)&sm.x[1][m][ks * 32 + quad * 8];
            half8 xh1 = *(half8*)&sm.x[0][16 + m][ks * 32 + quad * 8];
            half8 xl1 = *(half8*)&sm.x[1][16 + m][ks * 32 + quad * 8];
            acc[0][0] = __builtin_amdgcn_mfma_f32_16x16x32_f16(ql[0][ks], xh0, acc[0][0], 0, 0, 0);
            acc[0][1] = __builtin_amdgcn_mfma_f32_16x16x32_f16(ql[0][ks], xh1, acc[0][1], 0, 0, 0);
            acc[1][0] = __builtin_amdgcn_mfma_f32_16x16x32_f16(ql[1][ks], xh0, acc[1][0], 0, 0, 0);
            acc[1][1] = __builtin_amdgcn_mfma_f32_16x16x32_f16(ql[1][ks], xh1, acc[1][1], 0, 0, 0);
            acc[0][0] = __builtin_amdgcn_mfma_f32_16x16x32_f16(qh[0][ks], xl0, acc[0][0], 0, 0, 0);
            acc[0][1] = __builtin_amdgcn_mfma_f32_16x16x32_f16(qh[0][ks], xl1, acc[0][1], 0, 0, 0);
            acc[1][0] = __builtin_amdgcn_mfma_f32_16x16x32_f16(qh[1][ks], xl0, acc[1][0], 0, 0, 0);
            acc[1][1] = __builtin_amdgcn_mfma_f32_16x16x32_f16(qh[1][ks], xl1, acc[1][1], 0, 0, 0);
            acc[0][0] = __builtin_amdgcn_mfma_f32_16x16x32_f16(qh[0][ks], xh0, acc[0][0], 0, 0, 0);
            acc[0][1] = __builtin_amdgcn_mfma_f32_16x16x32_f16(qh[0][ks], xh1, acc[0][1], 0, 0, 0);
            acc[1][0] = __builtin_amdgcn_mfma_f32_16x16x32_f16(qh[1][ks], xh0, acc[1][0], 0, 0, 0);
            acc[1][1] = __builtin_amdgcn_mfma_f32_16x16x32_f16(qh[1][ks], xh1, acc[1][1], 0, 0, 0);
        }
        __syncthreads();   // all waves done reading x; safe to alias as dt
        // ---- epilogue: d = (qq - 2S) + xx, dump to dt ----------------------
        {
            float xx0 = XX[segbase + ct * 32 + m];
            float xx1 = XX[segbase + ct * 32 + 16 + m];
#pragma unroll
            for (int qs = 0; qs < 2; ++qs) {
                int qb = w * 32 + qs * 16 + quad * 4;
#pragma unroll
                for (int reg = 0; reg < 4; ++reg) {
                    float qq = QQs[qb + reg];
                    sm.dt[qb + reg][m]      = (qq - 2.0f * acc[qs][0][reg]) + xx0;
                    sm.dt[qb + reg][16 + m] = (qq - 2.0f * acc[qs][1][reg]) + xx1;
                }
            }
        }
        __syncthreads();
        // ---- selection: thread t (<128) owns query t, scans 32 candidates --
        if (t < 128) {
            const int ibase = segbase + ct * 32;
            for (int j = 0; j < 32; ++j) {
                float d = sm.dt[t][j];
                if (d < sd[15]) {
                    sd[15] = d; si[15] = ibase + j;   // ascending idx => strict < ok
#pragma unroll
                    for (int r = 15; r > 0; --r) {
                        if (sd[r] < sd[r - 1]) {
                            float td2 = sd[r]; sd[r] = sd[r - 1]; sd[r - 1] = td2;
                            int ti = si[r]; si[r] = si[r - 1]; si[r - 1] = ti;
                        }
                    }
                }
            }
        }
    }
    // ---- write sorted per-segment partial top-16 ---------------------------
    if (t < 128) {
        size_t o = ((size_t)(b * TD_S + qq8 * 128 + t)) * 64 + seg * 16;
#pragma unroll
        for (int r = 0; r < 16; ++r) { PD[o + r] = sd[r]; PI[o + r] = si[r]; }
    }
}

// Fallback (workspace too small for XH/XL): original fp32-staging version.
__global__ __launch_bounds__(256, 2)
void td_knn2(const float* __restrict__ feat, const float* __restrict__ XX,
             const int* __restrict__ FPSI, float* __restrict__ PD,
             int* __restrict__ PI) {
    __shared__ union {
        _Float16 x[2][32][264];
        float    dt[128][33];
    } sm;
    __shared__ float QQs[128];
    __shared__ int   QR[128];

    const int bx = blockIdx.x, t = threadIdx.x;
    const int b = bx & 15, r2 = bx >> 4;
    const int qq8 = r2 >> 2, seg = r2 & 3;
    const int cb = b * TD_P;
    const int segbase = cb + seg * 1024;

    if (t < 128) {
        int gr = FPSI[b * TD_S + qq8 * 128 + t];
        QR[t] = gr; QQs[t] = XX[gr];
    }
    __syncthreads();

    const int w = t >> 6, lane = t & 63;
    const int m = lane & 15, quad = lane >> 4;

    half8 qh[2][8], ql[2][8];
#pragma unroll
    for (int qs = 0; qs < 2; ++qs) {
        const float* qp = feat + (size_t)QR[w * 32 + qs * 16 + m] * 256;
#pragma unroll
        for (int ks = 0; ks < 8; ++ks) {
            float4 f0 = *(const float4*)(qp + ks * 32 + quad * 8);
            float4 f1 = *(const float4*)(qp + ks * 32 + quad * 8 + 4);
            float fv[8] = {f0.x, f0.y, f0.z, f0.w, f1.x, f1.y, f1.z, f1.w};
            half8 h, l;
#pragma unroll
            for (int j = 0; j < 8; ++j) {
                _Float16 hv = (_Float16)fv[j];
                h[j] = hv;
                l[j] = (_Float16)(fv[j] - (float)hv);
            }
            qh[qs][ks] = h; ql[qs][ks] = l;
        }
    }

    float sd[16]; int si[16];
#pragma unroll
    for (int r = 0; r < 16; ++r) { sd[r] = __builtin_inff(); si[r] = 0x7fffffff; }

    const int xrow = t >> 3, part = t & 7;

    for (int ct = 0; ct < 32; ++ct) {
        __syncthreads();
        {
            const float* xp = feat + (size_t)(segbase + ct * 32 + xrow) * 256 + part * 32;
#pragma unroll
            for (int s2 = 0; s2 < 4; ++s2) {
                float4 f0 = *(const float4*)(xp + s2 * 8);
                float4 f1 = *(const float4*)(xp + s2 * 8 + 4);
                float fv[8] = {f0.x, f0.y, f0.z, f0.w, f1.x, f1.y, f1.z, f1.w};
                half8 h, l;
#pragma unroll
                for (int j = 0; j < 8; ++j) {
                    _Float16 hv = (_Float16)fv[j];
                    h[j] = hv;
                    l[j] = (_Float16)(fv[j] - (float)hv);
                }
                *(half8*)&sm.x[0][xrow][part * 32 + s2 * 8] = h;
                *(half8*)&sm.x[1][xrow][part * 32 + s2 * 8] = l;
            }
        }
        __syncthreads();
        f32x4 acc[2][2];
        acc[0][0] = (f32x4)0.0f; acc[0][1] = (f32x4)0.0f;
        acc[1][0] = (f32x4)0.0f; acc[1][1] = (f32x4)0.0f;
#pragma unroll
        for (int ks = 0; ks < 8; ++ks) {
            half8 xh0 = *(half8*)&sm.x[0][m][ks * 32 + quad * 8];
            half8 xl0 = *(half8*)&sm.x[1][m][ks * 32 + quad * 8];
            half8 xh1 = *(half8*)&sm.x[0][16 + m][ks * 32 + quad * 8];
            half8 xl1 = *(half8*)&sm.x[1][16 + m][ks * 32 + quad * 8];
            acc[0][0] = __builtin_amdgcn_mfma_f32_16x16x32_f16(ql[0][ks], xh0, acc[0][0], 0, 0, 0);
            acc[0][1] = __builtin_amdgcn_mfma_f32_16x16x32_f16(ql[0][ks], xh1, acc[0][1], 0, 0, 0);
            acc[1][0] = __builtin_amdgcn_mfma_f32_16x16x32_f16(ql[1][ks], xh0, acc[1][0], 0, 0, 0);
            acc[1][1] = __builtin_amdgcn_mfma_f32_16x16x32_f16(ql[1][ks], xh1, acc[1][1], 0, 0, 0);
            acc[0][0] = __builtin_amdgcn_mfma_f32_16x16x32_f16(qh[0][ks], xl0, acc[0][0], 0, 0, 0);
            acc[0][1] = __builtin_amdgcn_mfma_f32_16x16x32_f16(qh[0][ks], xl1, acc[0][1], 0, 0, 0);
            acc[1][0] = __builtin_amdgcn_mfma_f32_16x16x32_f16(qh[1][ks], xl0, acc[1][0], 0, 0, 0);
            acc[1][1] = __builtin_amdgcn_mfma_f32_16x16x32_f16(qh[1][ks], xl1, acc[1][1], 0, 0, 0);
            acc[0][0] = __builtin_amdgcn_mfma_f32_16x16x32_f16(qh[0][ks], xh0, acc[0][0], 0, 0, 0);
            acc[0][1] = __builtin_amdgcn_mfma_f32_16x16x32_f16(qh[0][ks], xh1, acc[0][1], 0, 0, 0);
            acc[1][0] = __builtin_amdgcn_mfma_f32_16x16x32_f16(qh[1][ks], xh0, acc[1][0], 0, 0, 0);
            acc[1][1] = __builtin_amdgcn_mfma_f32_16x16x32_f16(qh[1][ks], xh1, acc[1][1], 0, 0, 0);
        }
        __syncthreads();
        {
            float xx0 = XX[segbase + ct * 32 + m];
            float xx1 = XX[segbase + ct * 32 + 16 + m];
#pragma unroll
            for (int qs = 0; qs < 2; ++qs) {
                int qb = w * 32 + qs * 16 + quad * 4;
#pragma unroll
                for (int reg = 0; reg < 4; ++reg) {
                    float qq = QQs[qb + reg];
                    sm.dt[qb + reg][m]      = (qq - 2.0f * acc[qs][0][reg]) + xx0;
                    sm.dt[qb + reg][16 + m] = (qq - 2.0f * acc[qs][1][reg]) + xx1;
                }
            }
        }
        __syncthreads();
        if (t < 128) {
            const int ibase = segbase + ct * 32;
            for (int j = 0; j < 32; ++j) {
                float d = sm.dt[t][j];
                if (d < sd[15]) {
                    sd[15] = d; si[15] = ibase + j;
#pragma unroll
                    for (int r = 15; r > 0; --r) {
                        if (sd[r] < sd[r - 1]) {
                            float td2 = sd[r]; sd[r] = sd[r - 1]; sd[r - 1] = td2;
                            int ti = si[r]; si[r] = si[r - 1]; si[r - 1] = ti;
                        }
                    }
                }
            }
        }
    }
    if (t < 128) {
        size_t o = ((size_t)(b * TD_S + qq8 * 128 + t)) * 64 + seg * 16;
#pragma unroll
        for (int r = 0; r < 16; ++r) { PD[o + r] = sd[r]; PI[o + r] = si[r]; }
    }
}

// Exact 4-way merge of sorted segment partials -> final top-16 per query.
__global__ __launch_bounds__(64)
void td_merge(const float* __restrict__ PD, const int* __restrict__ PI,
              int* __restrict__ NN) {
    __shared__ float ld_[64][65];
    __shared__ int   li_[64][65];
    const int bx = blockIdx.x, t = threadIdx.x;
    for (int j = 0; j < 64; ++j) {
        ld_[j][t] = PD[(size_t)bx * 4096 + j * 64 + t];
        li_[j][t] = PI[(size_t)bx * 4096 + j * 64 + t];
    }
    __syncthreads();
    int p[4] = {0, 0, 0, 0};
    int og = (bx * 64 + t) * TD_K;
    for (int r = 0; r < 16; ++r) {
        float bd = __builtin_inff(); int bi = 0x7fffffff; int bs = 0;
#pragma unroll
        for (int s = 0; s < 4; ++s) {
            if (p[s] < 16) {
                float d = ld_[t][s * 16 + p[s]];
                int   i = li_[t][s * 16 + p[s]];
                if (d < bd || (d == bd && i < bi)) { bd = d; bi = i; bs = s; }
            }
        }
        p[bs]++;
        NN[og + r] = bi;
    }
}

// 4 queries per block; cloud-grouped swizzle for L2 locality on H rows.
__global__ __launch_bounds__(256)
void td_maxpool(const unsigned short* __restrict__ H, const int* __restrict__ NN,
                const float* __restrict__ SS, float* __restrict__ outF) {
    __shared__ int nbr[64];
    const int bx = blockIdx.x, t = threadIdx.x;
    const int cloud = bx & 15, blk = bx >> 4;       // 256 blocks per cloud
    const int qbase = cloud * 1024 + blk * 4;
    if (t < 64) nbr[t] = NN[(size_t)qbase * 16 + t];
    __syncthreads();
    float sc0 = SS[2 * t], sc1 = SS[2 * t + 1];
    float sh0 = SS[512 + 2 * t], sh1 = SS[512 + 2 * t + 1];
#pragma unroll
    for (int qi = 0; qi < 4; ++qi) {
        float m0 = 0.0f, m1 = 0.0f;   // relu floor: max_k relu(v) = max(0, max_k v)
#pragma unroll
        for (int k = 0; k < 16; ++k) {
            int row = nbr[qi * 16 + k];
            unsigned u = ((const unsigned*)(H + (size_t)row * 512))[t];
            float lo = __uint_as_float(u << 16);
            float hi = __uint_as_float(u & 0xffff0000u);
            m0 = fmaxf(m0, fmaf(sc0, lo, sh0));
            m1 = fmaxf(m1, fmaf(sc1, hi, sh1));
        }
        float2 o; o.x = m0; o.y = m1;
        *(float2*)&outF[(size_t)(qbase + qi) * 512 + 2 * t] = o;
    }
}

extern "C" void kernel_launch(void* const* d_in, const int* in_sizes, int n_in,
                              void* d_out, int out_size, void* d_ws, size_t ws_size,
                              hipStream_t stream) {
    const float* feat  = (const float*)d_in[0];
    const float* pos   = (const float*)d_in[1];
    // d_in[2] = batch (int32): unused, value is row/P by construction
    const float* W     = (const float*)d_in[3];
    const float* bias  = (const float*)d_in[4];
    const float* gamma = (const float*)d_in[5];
    const float* beta  = (const float*)d_in[6];

    char* ws = (char*)d_ws;
    unsigned short* H = (unsigned short*)ws;            // 67,108,864 B (bf16 h)
    float* XX  = (float*)(ws + 67108864);               //    262,144 B
    int*   FPSI= (int*)  (ws + 67371008);               //     65,536 B
    int*   NN  = (int*)  (ws + 67436544);               //  1,048,576 B
    float* P1  = (float*)(ws + 68485120);               //    524,288 B used
    float* P2  = (float*)(ws + 69533696);               //    524,288 B used
    float* SS  = (float*)(ws + 70582272);               //      4,096 B
    float* PD  = (float*)(ws + 70586368);               //  4,194,304 B
    int*   PI  = (int*)  (ws + 74780672);               //  4,194,304 B
    // fp16 hi/lo split of features (precomputed in fused shadow), 32 MB each
    const size_t XH_OFF = 78974976, XL_OFF = 112529408, WS_NEED = 146083840;
    bool hx = ws_size >= WS_NEED;
    _Float16* XH = hx ? (_Float16*)(ws + XH_OFF) : nullptr;
    _Float16* XL = hx ? (_Float16*)(ws + XL_OFF) : nullptr;

    float* outF = (float*)d_out;
    float* outP = outF + (size_t)TD_B * TD_S * TD_OUTF;   // 8,388,608
    float* outB = outP + (size_t)TD_B * TD_S * 3;         // +49,152

    td_fused  <<<2056, 512, 0, stream>>>(feat, pos, W, bias, H, XX, FPSI, outP, outB, XH, XL);
    td_stats  <<<256, 256, 0, stream>>>(H, P1, P2);
    td_bnfin  <<<1, 512, 0, stream>>>(P1, P2, gamma, beta, SS);
    if (hx) td_knn2h<<<512, 256, 0, stream>>>(XH, XL, XX, FPSI, PD, PI);
    else    td_knn2 <<<512, 256, 0, stream>>>(feat, XX, FPSI, PD, PI);
    td_merge  <<<256, 64, 0, stream>>>(PD, PI, NN);
    td_maxpool<<<TD_B * 256, 256, 0, stream>>>(H, NN, SS, outF);
}

// Round 3
// 1180.979 us; speedup vs baseline: 1.0681x; 1.0681x over previous
//
#include <hip/hip_runtime.h>
#include <cstddef>

// TransitionDown: B=16 clouds, P=4096 pts, S=1024 fps samples, K=16 knn,
// IN_F=256, OUT_F=512.
//
// SINGLE mega-kernel: all stages fused, sequenced by device-scope flags so the
// serial FPS chain (~620us on 16 CUs) shadows everything else on the other
// 240 CUs. Block-index layout (producers strictly before consumers):
//   [0,16)        FPS (round-0 proven core) + progress publish every 128 samples
//   [16,1040)     MLP GEMM fp32 -> h bf16; completion counter
//   [1040,1552)   KNN: 2 q-groups x 512-cand segment, fp16-split MFMA,
//                 self-contained norms; spins on FPS progress only
//   [1552,1808)   BN partial sums (spin: gemm done)
//   [1808]        BN finalize -> scale/shift (spin: stats done)
//   [1809,2065)   8-way merge of segment top-16 (spin: its 8 knn blocks)
//   [2065,4113)   maxpool 8 queries/block (spin: merge block + bnfin)
// flags (workspace, memset to 0 each launch):
//   [0..15] fps chunk progress per cloud, [16] gemm, [17] stats, [18] bnfin,
//   [24+b*4+qqp] knn seg counters (target 8), [96+mb] merge done.

#define TD_B   16
#define TD_P   4096
#define TD_S   1024
#define TD_K   16
#define TD_INF 256
#define TD_OUTF 512

typedef __attribute__((ext_vector_type(8))) _Float16 half8;
typedef __attribute__((ext_vector_type(4))) float    f32x4;
typedef __attribute__((ext_vector_type(2))) float    v2f;

__device__ __forceinline__ unsigned short f2bf(float x) {
    unsigned u = __float_as_uint(x);
    unsigned r = (u + 0x7fffu + ((u >> 16) & 1u)) >> 16;   // RNE
    return (unsigned short)r;
}

__device__ __forceinline__ int ld_acq(const int* p) {
    return __hip_atomic_load(p, __ATOMIC_ACQUIRE, __HIP_MEMORY_SCOPE_AGENT);
}
__device__ __forceinline__ void st_rel(int* p, int v) {
    __hip_atomic_store(p, v, __ATOMIC_RELEASE, __HIP_MEMORY_SCOPE_AGENT);
}
__device__ __forceinline__ void add_rel(int* p, int v) {
    __hip_atomic_fetch_add(p, v, __ATOMIC_RELEASE, __HIP_MEMORY_SCOPE_AGENT);
}

struct FpsSm {
    float4 p4[TD_P];                 // 64 KB
    int    sel[TD_S];                // 4 KB
    unsigned long long kw[2][4];     // parity-buffered per-wave argmax keys
};
struct GemmSm {
    float As[16 * 260];
    float Bs[16 * 128];
};
struct KnnSm {
    union {
        _Float16 x[2][32][264];      // [hi/lo][c][k], row pad 8 halfs (33792 B)
        float    dt[256][33];        // aliased after MFMA (33792 B)
    } u;
    float QQs[256];
    int   QR[256];
    float xxs[32];
};
struct MergeSm {
    float ld[64][130];               // 128 used, pad 2 (bank spread)
    int   li[64][130];
};
struct MaxpSm { int nbr[128]; };
union SmU {
    FpsSm f; GemmSm g; KnnSm k; MergeSm m; MaxpSm mp;
    char pad_[84000];                // 1 block/CU: FPS keeps private CUs
};

// One level of a wave64 max-reduce on a positive-double key via paired 32-bit
// DPP + v_max_f64 (key hi=fp32 bits of min_d (never NaN-pattern), lo=~idx;
// positive finite doubles => fmax == bitwise u64 max, tie -> lowest idx).
#define TD_DPPSTEPD(kd_, ctl, bc)                                                       \
    {                                                                                   \
        long long ki_ = __double_as_longlong(kd_);                                      \
        unsigned yh_ = (unsigned)__builtin_amdgcn_update_dpp(                           \
            0, (int)((unsigned long long)ki_ >> 32), (ctl), 0xf, 0xf, (bc));            \
        unsigned yl_ = (unsigned)__builtin_amdgcn_update_dpp(                           \
            0, (int)(unsigned)(unsigned long long)ki_, (ctl), 0xf, 0xf, (bc));          \
        kd_ = fmax(kd_, __hiloint2double((int)yh_, (int)yl_));                          \
    }

__global__ __launch_bounds__(512)
void td_all(const float* __restrict__ feat, const float* __restrict__ pos,
            const float* __restrict__ W, const float* __restrict__ bias,
            const float* __restrict__ gamma, const float* __restrict__ beta,
            unsigned short* __restrict__ H, int* __restrict__ FPSI,
            int* __restrict__ NN, float* __restrict__ P1, float* __restrict__ P2,
            float* __restrict__ SS, float* __restrict__ PD, int* __restrict__ PI,
            float* __restrict__ outF, float* __restrict__ outP,
            float* __restrict__ outB, int* __restrict__ flags) {
    __shared__ SmU sm;
    const int bx = blockIdx.x;
    const int t  = threadIdx.x;

    if (bx < 16) {
        // ================= FPS: round-0 core, 256 active threads =============
        __builtin_amdgcn_s_setprio(2);
        const int b = bx;
        const int w = t >> 6;
        v2f px[8], py[8], pz[8], md[8];
        int ni0[8], ni1[8];
        float lx = 0.0f, ly = 0.0f, lz = 0.0f;
        if (t < 256) {
#pragma unroll
            for (int j = 0; j < 8; ++j) {
                int p0 = j * 512 + t, p1 = p0 + 256;
                const float* q0 = pos + (size_t)(b * TD_P + p0) * 3;
                const float* q1 = pos + (size_t)(b * TD_P + p1) * 3;
                float x0 = q0[0], y0 = q0[1], z0 = q0[2];
                float x1 = q1[0], y1 = q1[1], z1 = q1[2];
                px[j] = (v2f){x0, x1}; py[j] = (v2f){y0, y1}; pz[j] = (v2f){z0, z1};
                sm.f.p4[p0] = make_float4(x0, y0, z0, 0.0f);
                sm.f.p4[p1] = make_float4(x1, y1, z1, 0.0f);
                md[j] = (v2f){__builtin_inff(), __builtin_inff()};
                ni0[j] = ~p0; ni1[j] = ~p1;
            }
            if (t == 0) sm.f.sel[0] = 0;
        }
        __syncthreads();
        if (t < 256) { float4 wp = sm.f.p4[0]; lx = wp.x; ly = wp.y; lz = wp.z; }
        for (int s = 0; s < TD_S - 1; ++s) {
            const int par = s & 1;
            if (t < 256) {
                double k[16];
                {
#pragma clang fp contract(off)
                    v2f l2x = (v2f){lx, lx}, l2y = (v2f){ly, ly}, l2z = (v2f){lz, lz};
#pragma unroll
                    for (int j = 0; j < 8; ++j) {
                        v2f dx = px[j] - l2x;
                        v2f dy = py[j] - l2y;
                        v2f dz = pz[j] - l2z;
                        v2f sx = dx * dx;
                        v2f sy = dy * dy;
                        v2f sz = dz * dz;
                        v2f dd = (sx + sy) + sz;
                        md[j] = __builtin_elementwise_min(md[j], dd);
                        k[2 * j]     = __hiloint2double(__float_as_int(md[j].x), ni0[j]);
                        k[2 * j + 1] = __hiloint2double(__float_as_int(md[j].y), ni1[j]);
                    }
                }
#pragma unroll
                for (int st = 8; st > 0; st >>= 1)
#pragma unroll
                    for (int i = 0; i < st; ++i) k[i] = fmax(k[i], k[i + st]);
                double tk = k[0];
                TD_DPPSTEPD(tk, 0x111, true)    // row_shr:1
                TD_DPPSTEPD(tk, 0x112, true)    // row_shr:2
                TD_DPPSTEPD(tk, 0x114, true)    // row_shr:4
                TD_DPPSTEPD(tk, 0x118, true)    // row_shr:8
                TD_DPPSTEPD(tk, 0x142, false)   // row_bcast:15
                TD_DPPSTEPD(tk, 0x143, false)   // row_bcast:31
                if ((t & 63) == 63)
                    sm.f.kw[par][w] = (unsigned long long)__double_as_longlong(tk);
            }
            __syncthreads();
            if (t < 256) {
                const double2* kd = (const double2*)sm.f.kw[par];
                double2 va = kd[0], vb = kd[1];
                double gk = fmax(fmax(va.x, va.y), fmax(vb.x, vb.y));
                unsigned idx = ~(unsigned)__double2loint(gk);
                if (t == 0) sm.f.sel[s + 1] = (int)idx;
                float4 wp = sm.f.p4[idx];
                lx = wp.x; ly = wp.y; lz = wp.z;
            }
            // progress publish: chunk c = samples [c*128,(c+1)*128) final.
            // wave 0 only (same wave as sel writer => LDS program-order safe).
            if (t < 64 && (s & 127) == 127 && s < 896) {
                int c = s >> 7;
                int i0 = c * 128 + 2 * t;
                FPSI[b * TD_S + i0]     = b * TD_P + sm.f.sel[i0];
                FPSI[b * TD_S + i0 + 1] = b * TD_P + sm.f.sel[i0 + 1];
                __threadfence();
                if (t == 0) st_rel(flags + b, c + 1);
            }
        }
        __syncthreads();
        for (int s = t; s < TD_S; s += 512) {
            int li = sm.f.sel[s];
            int og = b * TD_S + s;
            float4 wp = sm.f.p4[li];
            outP[og * 3 + 0] = wp.x;
            outP[og * 3 + 1] = wp.y;
            outP[og * 3 + 2] = wp.z;
            outB[og] = (float)b;
            FPSI[og] = b * TD_P + li;
        }
        __syncthreads();
        if (t == 0) { __threadfence(); st_rel(flags + b, 8); }
    } else if (bx < 16 + 1024) {
        // ================= MLP GEMM: 256x128 tile, 8x8 micro =================
        const int gb = bx - 16;
        const int mb = gb >> 2, nb = gb & 3;
        const int tm = t >> 4, tn = t & 15;
        float acc[8][8];
#pragma unroll
        for (int i = 0; i < 8; ++i)
#pragma unroll
            for (int j = 0; j < 8; ++j) acc[i][j] = 0.0f;
        float* As = sm.g.As;
        float* Bs = sm.g.Bs;
        for (int kc = 0; kc < 16; ++kc) {
#pragma unroll
            for (int p2 = 0; p2 < 2; ++p2) {
                int f4 = t + 512 * p2;
                int r = f4 >> 2, c4 = f4 & 3;
                float4 v = *(const float4*)&feat[(size_t)(mb * 256 + r) * 256 + kc * 16 + c4 * 4];
                As[(c4 * 4 + 0) * 260 + r] = v.x;
                As[(c4 * 4 + 1) * 260 + r] = v.y;
                As[(c4 * 4 + 2) * 260 + r] = v.z;
                As[(c4 * 4 + 3) * 260 + r] = v.w;
            }
            {
                int kk = t >> 5, n4 = t & 31;
                float4 v = *(const float4*)&W[(size_t)(kc * 16 + kk) * 512 + nb * 128 + n4 * 4];
                *(float4*)&Bs[kk * 128 + n4 * 4] = v;
            }
            __syncthreads();
#pragma unroll
            for (int kk = 0; kk < 16; ++kk) {
                float4 a0 = *(float4*)&As[kk * 260 + tm * 8];
                float4 a1 = *(float4*)&As[kk * 260 + tm * 8 + 4];
                float4 b0 = *(float4*)&Bs[kk * 128 + tn * 8];
                float4 b1 = *(float4*)&Bs[kk * 128 + tn * 8 + 4];
                float av[8] = {a0.x, a0.y, a0.z, a0.w, a1.x, a1.y, a1.z, a1.w};
                float bv2[8] = {b0.x, b0.y, b0.z, b0.w, b1.x, b1.y, b1.z, b1.w};
#pragma unroll
                for (int i = 0; i < 8; ++i)
#pragma unroll
                    for (int j = 0; j < 8; ++j)
                        acc[i][j] = fmaf(av[i], bv2[j], acc[i][j]);
            }
            __syncthreads();
        }
        float4 bb0 = *(const float4*)&bias[nb * 128 + tn * 8];
        float4 bb1 = *(const float4*)&bias[nb * 128 + tn * 8 + 4];
        float bsv[8] = {bb0.x, bb0.y, bb0.z, bb0.w, bb1.x, bb1.y, bb1.z, bb1.w};
#pragma unroll
        for (int i = 0; i < 8; ++i) {
            int row = mb * 256 + tm * 8 + i;
            uint4 pk;
            pk.x = (unsigned)f2bf(acc[i][0] + bsv[0]) | ((unsigned)f2bf(acc[i][1] + bsv[1]) << 16);
            pk.y = (unsigned)f2bf(acc[i][2] + bsv[2]) | ((unsigned)f2bf(acc[i][3] + bsv[3]) << 16);
            pk.z = (unsigned)f2bf(acc[i][4] + bsv[4]) | ((unsigned)f2bf(acc[i][5] + bsv[5]) << 16);
            pk.w = (unsigned)f2bf(acc[i][6] + bsv[6]) | ((unsigned)f2bf(acc[i][7] + bsv[7]) << 16);
            *(uint4*)&H[(size_t)row * 512 + nb * 128 + tn * 8] = pk;
        }
        __syncthreads();
        if (t == 0) { __threadfence(); add_rel(flags + 16, 1); }
    } else if (bx < 1552) {
        // ================= KNN: 2 q-groups x 512-cand segment ================
        const int kb = bx - 1040;                 // [0,512)
        const int b = kb & 15, r2 = kb >> 4;      // r2 in [0,32)
        const int qqp = r2 >> 3, seg = r2 & 7;
        const int segbase = b * TD_P + seg * 512;
        const int qbase = b * TD_S + qqp * 256;
        if (t == 0) {
            while (ld_acq(flags + b) < 2 * qqp + 2) __builtin_amdgcn_s_sleep(16);
        }
        __syncthreads();
        if (t < 256) sm.k.QR[t] = FPSI[qbase + t];
        __syncthreads();

        const int w = t >> 6, lane = t & 63;
        const int m = lane & 15, quad = lane >> 4;

        // Q fragments (each wave owns 32 queries) + query norms via shuffles
        half8 qh[2][8], ql[2][8];
#pragma unroll
        for (int qs = 0; qs < 2; ++qs) {
            const float* qp = feat + (size_t)sm.k.QR[w * 32 + qs * 16 + m] * 256;
            float qq2 = 0.0f;
#pragma unroll
            for (int ks = 0; ks < 8; ++ks) {
                float4 f0 = *(const float4*)(qp + ks * 32 + quad * 8);
                float4 f1 = *(const float4*)(qp + ks * 32 + quad * 8 + 4);
                float fv[8] = {f0.x, f0.y, f0.z, f0.w, f1.x, f1.y, f1.z, f1.w};
                half8 h, l;
#pragma unroll
                for (int j = 0; j < 8; ++j) {
                    _Float16 hv = (_Float16)fv[j];
                    h[j] = hv;
                    l[j] = (_Float16)(fv[j] - (float)hv);
                    qq2 = fmaf(fv[j], fv[j], qq2);
                }
                qh[qs][ks] = h; ql[qs][ks] = l;
            }
            qq2 += __shfl_xor(qq2, 16, 64);
            qq2 += __shfl_xor(qq2, 32, 64);
            if (quad == 0) sm.k.QQs[w * 32 + qs * 16 + m] = qq2;
        }

        float sd[16]; int si[16];
#pragma unroll
        for (int r = 0; r < 16; ++r) { sd[r] = __builtin_inff(); si[r] = 0x7fffffff; }

        const int xrow = t >> 4, part = t & 15;

        for (int ct = 0; ct < 16; ++ct) {
            __syncthreads();   // prev selection done reading dt (aliases x)
            // ---- stage 32 cands x 256k fp32->fp16 hi/lo + candidate norms ---
            {
                const float* xp = feat + (size_t)(segbase + ct * 32 + xrow) * 256 + part * 16;
                float4 f0 = *(const float4*)(xp);
                float4 f1 = *(const float4*)(xp + 4);
                float4 f2 = *(const float4*)(xp + 8);
                float4 f3 = *(const float4*)(xp + 12);
                float fv[16] = {f0.x, f0.y, f0.z, f0.w, f1.x, f1.y, f1.z, f1.w,
                                f2.x, f2.y, f2.z, f2.w, f3.x, f3.y, f3.z, f3.w};
                half8 h0, h1, l0, l1;
                float cn = 0.0f;
#pragma unroll
                for (int j = 0; j < 8; ++j) {
                    _Float16 hv = (_Float16)fv[j];
                    h0[j] = hv; l0[j] = (_Float16)(fv[j] - (float)hv);
                    cn = fmaf(fv[j], fv[j], cn);
                }
#pragma unroll
                for (int j = 0; j < 8; ++j) {
                    float v = fv[8 + j];
                    _Float16 hv = (_Float16)v;
                    h1[j] = hv; l1[j] = (_Float16)(v - (float)hv);
                    cn = fmaf(v, v, cn);
                }
                *(half8*)&sm.k.u.x[0][xrow][part * 16]     = h0;
                *(half8*)&sm.k.u.x[0][xrow][part * 16 + 8] = h1;
                *(half8*)&sm.k.u.x[1][xrow][part * 16]     = l0;
                *(half8*)&sm.k.u.x[1][xrow][part * 16 + 8] = l1;
                cn += __shfl_xor(cn, 1, 64);
                cn += __shfl_xor(cn, 2, 64);
                cn += __shfl_xor(cn, 4, 64);
                cn += __shfl_xor(cn, 8, 64);
                if (part == 0) sm.k.xxs[xrow] = cn;
            }
            __syncthreads();
            // ---- MFMA: all 8 waves, pass-major, 4 independent acc chains ----
            f32x4 acc[2][2];
            acc[0][0] = (f32x4)0.0f; acc[0][1] = (f32x4)0.0f;
            acc[1][0] = (f32x4)0.0f; acc[1][1] = (f32x4)0.0f;
#pragma unroll
            for (int ks = 0; ks < 8; ++ks) {
                half8 xh0 = *(half8*)&sm.k.u.x[0][m][ks * 32 + quad * 8];
                half8 xl0 = *(half8*)&sm.k.u.x[1][m][ks * 32 + quad * 8];
                half8 xh1 = *(half8*)&sm.k.u.x[0][16 + m][ks * 32 + quad * 8];
                half8 xl1 = *(half8*)&sm.k.u.x[1][16 + m][ks * 32 + quad * 8];
                acc[0][0] = __builtin_amdgcn_mfma_f32_16x16x32_f16(ql[0][ks], xh0, acc[0][0], 0, 0, 0);
                acc[0][1] = __builtin_amdgcn_mfma_f32_16x16x32_f16(ql[0][ks], xh1, acc[0][1], 0, 0, 0);
                acc[1][0] = __builtin_amdgcn_mfma_f32_16x16x32_f16(ql[1][ks], xh0, acc[1][0], 0, 0, 0);
                acc[1][1] = __builtin_amdgcn_mfma_f32_16x16x32_f16(ql[1][ks], xh1, acc[1][1], 0, 0, 0);
                acc[0][0] = __builtin_amdgcn_mfma_f32_16x16x32_f16(qh[0][ks], xl0, acc[0][0], 0, 0, 0);
                acc[0][1] = __builtin_amdgcn_mfma_f32_16x16x32_f16(qh[0][ks], xl1, acc[0][1], 0, 0, 0);
                acc[1][0] = __builtin_amdgcn_mfma_f32_16x16x32_f16(qh[1][ks], xl0, acc[1][0], 0, 0, 0);
                acc[1][1] = __builtin_amdgcn_mfma_f32_16x16x32_f16(qh[1][ks], xl1, acc[1][1], 0, 0, 0);
                acc[0][0] = __builtin_amdgcn_mfma_f32_16x16x32_f16(qh[0][ks], xh0, acc[0][0], 0, 0, 0);
                acc[0][1] = __builtin_amdgcn_mfma_f32_16x16x32_f16(qh[0][ks], xh1, acc[0][1], 0, 0, 0);
                acc[1][0] = __builtin_amdgcn_mfma_f32_16x16x32_f16(qh[1][ks], xh0, acc[1][0], 0, 0, 0);
                acc[1][1] = __builtin_amdgcn_mfma_f32_16x16x32_f16(qh[1][ks], xh1, acc[1][1], 0, 0, 0);
            }
            __syncthreads();   // all waves done reading x; safe to alias as dt
            // ---- epilogue: d = (qq - 2S) + xx -> dt -------------------------
            {
                float xx0 = sm.k.xxs[m];
                float xx1 = sm.k.xxs[16 + m];
#pragma unroll
                for (int qs = 0; qs < 2; ++qs) {
                    int qb = w * 32 + qs * 16 + quad * 4;
#pragma unroll
                    for (int reg = 0; reg < 4; ++reg) {
                        float qq = sm.k.QQs[qb + reg];
                        sm.k.u.dt[qb + reg][m]      = (qq - 2.0f * acc[qs][0][reg]) + xx0;
                        sm.k.u.dt[qb + reg][16 + m] = (qq - 2.0f * acc[qs][1][reg]) + xx1;
                    }
                }
            }
            __syncthreads();
            // ---- selection: thread t (<256) owns query t --------------------
            if (t < 256) {
                const int ibase = segbase + ct * 32;
                for (int j = 0; j < 32; ++j) {
                    float d = sm.k.u.dt[t][j];
                    if (d < sd[15]) {
                        sd[15] = d; si[15] = ibase + j;
#pragma unroll
                        for (int r = 15; r > 0; --r) {
                            if (sd[r] < sd[r - 1]) {
                                float td2 = sd[r]; sd[r] = sd[r - 1]; sd[r - 1] = td2;
                                int ti = si[r]; si[r] = si[r - 1]; si[r - 1] = ti;
                            }
                        }
                    }
                }
            }
        }
        if (t < 256) {
            size_t o = ((size_t)(qbase + t)) * 128 + seg * 16;
#pragma unroll
            for (int r = 0; r < 16; ++r) { PD[o + r] = sd[r]; PI[o + r] = si[r]; }
        }
        __syncthreads();
        if (t == 0) { __threadfence(); add_rel(flags + 24 + b * 4 + qqp, 1); }
    } else if (bx < 1808) {
        // ================= BN partial sums (needs all GEMM) ==================
        const int rb = bx - 1552;
        if (t == 0) {
            while (ld_acq(flags + 16) < 1024) __builtin_amdgcn_s_sleep(32);
        }
        __syncthreads();
        if (t < 256) {
            float s1a = 0, s2a = 0, s1b = 0, s2b = 0;
            for (int r = 0; r < 256; ++r) {
                const unsigned* hp = (const unsigned*)(H + (size_t)(rb * 256 + r) * 512);
                unsigned u = hp[t];
                float lo = __uint_as_float(u << 16);
                float hi = __uint_as_float(u & 0xffff0000u);
                s1a += lo; s2a = fmaf(lo, lo, s2a);
                s1b += hi; s2b = fmaf(hi, hi, s2b);
            }
            P1[rb * 512 + 2 * t] = s1a; P1[rb * 512 + 2 * t + 1] = s1b;
            P2[rb * 512 + 2 * t] = s2a; P2[rb * 512 + 2 * t + 1] = s2b;
        }
        __syncthreads();
        if (t == 0) { __threadfence(); add_rel(flags + 17, 1); }
    } else if (bx == 1808) {
        // ================= BN finalize -> scale/shift ========================
        if (t == 0) {
            while (ld_acq(flags + 17) < 256) __builtin_amdgcn_s_sleep(32);
        }
        __syncthreads();
        {
            const int ch = t;
            float s1 = 0, s2 = 0;
            for (int rb2 = 0; rb2 < 256; ++rb2) {
                s1 += P1[rb2 * 512 + ch]; s2 += P2[rb2 * 512 + ch];
            }
            const float invN = 1.0f / 65536.0f;
            float mu  = s1 * invN;
            float var = s2 * invN - mu * mu;
            float sc  = gamma[ch] * (1.0f / sqrtf(var + 1e-5f));
            float sh  = beta[ch] - mu * sc;
            SS[ch] = sc; SS[512 + ch] = sh;
        }
        __syncthreads();
        if (t == 0) { __threadfence(); st_rel(flags + 18, 1); }
    } else if (bx < 2065) {
        // ================= 8-way merge: 64 queries/block =====================
        const int mb = bx - 1809;                 // [0,256)
        const int cloud = mb >> 4, qqp = (mb >> 2) & 3;
        if (t == 0) {
            while (ld_acq(flags + 24 + cloud * 4 + qqp) < 8) __builtin_amdgcn_s_sleep(16);
        }
        __syncthreads();
        for (int i = t; i < 64 * 128; i += 512) {
            int qi = i >> 7, j = i & 127;
            sm.m.ld[qi][j] = PD[(size_t)mb * 8192 + i];
            sm.m.li[qi][j] = PI[(size_t)mb * 8192 + i];
        }
        __syncthreads();
        if (t < 64) {
            float sd[16]; int si[16];
#pragma unroll
            for (int r = 0; r < 16; ++r) { sd[r] = __builtin_inff(); si[r] = 0x7fffffff; }
            // scan order = seg-major ascending => global index ascending;
            // strict-< insertion keeps lowest index on ties (matches ref).
            for (int j = 0; j < 128; ++j) {
                float d = sm.m.ld[t][j];
                if (d < sd[15]) {
                    sd[15] = d; si[15] = sm.m.li[t][j];
#pragma unroll
                    for (int r = 15; r > 0; --r) {
                        if (sd[r] < sd[r - 1]) {
                            float td2 = sd[r]; sd[r] = sd[r - 1]; sd[r - 1] = td2;
                            int ti = si[r]; si[r] = si[r - 1]; si[r - 1] = ti;
                        }
                    }
                }
            }
            int og = (mb * 64 + t) * TD_K;
#pragma unroll
            for (int r = 0; r < 16; ++r) NN[og + r] = si[r];
        }
        __syncthreads();
        if (t == 0) { __threadfence(); st_rel(flags + 96 + mb, 1); }
    } else {
        // ================= maxpool: 8 queries/block ==========================
        const int pb = bx - 2065;                 // [0,2048)
        const int qbase8 = pb * 8;
        const int mrg = qbase8 >> 6;
        if (t == 0) {
            while (ld_acq(flags + 96 + mrg) == 0) __builtin_amdgcn_s_sleep(16);
            while (ld_acq(flags + 18) == 0) __builtin_amdgcn_s_sleep(16);
        }
        __syncthreads();
        if (t < 128) sm.mp.nbr[t] = NN[(size_t)qbase8 * 16 + t];
        __syncthreads();
        const int hq = t >> 8, tc = t & 255;
        float sc0 = SS[2 * tc], sc1 = SS[2 * tc + 1];
        float sh0 = SS[512 + 2 * tc], sh1 = SS[512 + 2 * tc + 1];
#pragma unroll
        for (int qi = 0; qi < 4; ++qi) {
            const int q = hq * 4 + qi;
            float m0 = 0.0f, m1 = 0.0f;   // relu floor
#pragma unroll
            for (int k = 0; k < 16; ++k) {
                int row = sm.mp.nbr[q * 16 + k];
                unsigned u = ((const unsigned*)(H + (size_t)row * 512))[tc];
                float lo = __uint_as_float(u << 16);
                float hi = __uint_as_float(u & 0xffff0000u);
                m0 = fmaxf(m0, fmaf(sc0, lo, sh0));
                m1 = fmaxf(m1, fmaf(sc1, hi, sh1));
            }
            float2 o; o.x = m0; o.y = m1;
            *(float2*)&outF[(size_t)(qbase8 + q) * 512 + 2 * tc] = o;
        }
    }
}

extern "C" void kernel_launch(void* const* d_in, const int* in_sizes, int n_in,
                              void* d_out, int out_size, void* d_ws, size_t ws_size,
                              hipStream_t stream) {
    const float* feat  = (const float*)d_in[0];
    const float* pos   = (const float*)d_in[1];
    // d_in[2] = batch (int32): unused, value is row/P by construction
    const float* W     = (const float*)d_in[3];
    const float* bias  = (const float*)d_in[4];
    const float* gamma = (const float*)d_in[5];
    const float* beta  = (const float*)d_in[6];

    char* ws = (char*)d_ws;
    int* flags        = (int*)ws;                        //      2,048 B (memset)
    unsigned short* H = (unsigned short*)(ws + 4096);    // 67,108,864 B
    int*   FPSI = (int*)  (ws + 67112960);               //     65,536 B
    int*   NN   = (int*)  (ws + 67178496);               //  1,048,576 B
    float* P1   = (float*)(ws + 68227072);               //    524,288 B
    float* P2   = (float*)(ws + 68751360);               //    524,288 B
    float* SS   = (float*)(ws + 69275648);               //      4,096 B
    float* PD   = (float*)(ws + 69279744);               //  8,388,608 B
    int*   PI   = (int*)  (ws + 77668352);               //  8,388,608 B

    float* outF = (float*)d_out;
    float* outP = outF + (size_t)TD_B * TD_S * TD_OUTF;
    float* outB = outP + (size_t)TD_B * TD_S * 3;

    hipMemsetAsync(flags, 0, 2048, stream);
    td_all<<<4113, 512, 0, stream>>>(feat, pos, W, bias, gamma, beta,
                                     H, FPSI, NN, P1, P2, SS, PD, PI,
                                     outF, outP, outB, flags);
}